// Round 4
// baseline (674.510 us; speedup 1.0000x reference)
//
#include <hip/hip_runtime.h>
#include <hip/hip_cooperative_groups.h>

#define NN 50000
#define EE 800000
#define CC 64
#define HH 2
#define LL 3
#define CAP 64     // slots per node (Poisson(16): P(>=64) ~ 1e-13)
#define NB 782     // dst buckets of 64 nodes: (50000+63)/64
#define BCAP 1280  // per-bucket capacity (mean 1023, +8 sigma)
#define CHUNK 2048 // edges per bin chunk (256 threads/block in fused kernel)
#define NCHUNK ((EE + CHUNK - 1) / CHUNK)   // 391
#define NQ ((NN + 3) / 4)                   // 12500 node-quads
#define MAXGRID 1536                        // 6 blocks/CU x 256 CU

// R15: single cooperative kernel. R13 measured ~7-9us of fixed overhead per
// dispatch gap (200 total - 138 gat - 22 build - 2 memset = ~38 over 5 gaps);
// fusing 6 dispatches -> 1 trades 5 gaps for 5 grid.sync()s (~1-3us each).
// Build reverted to R13 counting sort: R14's direct-atomic build showed 27x
// HBM write amplification (44MB for 1.6MB of slots) from temporally-scattered
// 2B stores across 8 non-coherent XCD L2s; k_place's block-owned 8KB windows
// fill lines locally in time. All phase bodies are the proven R13 code.

#define LEAKY(v) fmaxf((v), 0.2f * (v))

template <int CTRL>
__device__ __forceinline__ float dpp_add(float v) {
    int t = __builtin_amdgcn_update_dpp(0, __float_as_int(v), CTRL, 0xF, 0xF, true);
    return v + __int_as_float(t);
}

// sum over the 16 lanes of a subgroup (subgroups are 16-lane aligned);
// fused v_add_f32_dpp on the VALU pipe — no ds_swizzle/lgkm stall (R13 win)
__device__ __forceinline__ float red16(float v) {
    v = dpp_add<0xB1>(v);    // quad_perm [1,0,3,2] = lane^1
    v = dpp_add<0x4E>(v);    // quad_perm [2,3,0,1] = lane^2
    v = dpp_add<0x141>(v);   // row_half_mirror     = lane^4 (quads uniform)
    v = dpp_add<0x140>(v);   // row_mirror          = lane^8 (halves uniform)
    return v;
}

template <bool FIRST>
__device__ __forceinline__ void gat_phase(const float* __restrict__ h,
                                          const int* __restrict__ cnt,
                                          const unsigned short* __restrict__ slots,
                                          const float* __restrict__ att_l,
                                          const float* __restrict__ bias_l,
                                          float* __restrict__ h_out,
                                          float* __restrict__ acc) {
    int wid = threadIdx.x >> 6;
    int lane = threadIdx.x & 63;
    int sub = lane >> 4, q = lane & 15;
    unsigned qb = (unsigned)q << 4;              // byte offset of quad in a row
    const char* hb = (const char*)h;
    float4 a0q = ((const float4*)att_l)[q];
    float4 a1q = ((const float4*)att_l)[16 + q];
    float4 b4 = ((const float4*)bias_l)[q];

    for (int g = blockIdx.x; g < NQ; g += gridDim.x) {
        int node = g * 4 + wid;
        if (node >= NN) continue;                // wave-uniform; no barriers inside

        float4 hd = *(const float4*)(hb + (((unsigned)node << 8) + qb));
        int deg = cnt[node];
        if (deg > CAP) deg = CAP;
        const unsigned* rowu = (const unsigned*)(slots + (size_t)node * CAP);

        float s0, s1;
        float4 A0, A1;

        // self-loop: all 4 subgroups, weight 1/4 (merge restores 1x) — no branch
        {
            float vx = LEAKY(2.f * hd.x), vy = LEAKY(2.f * hd.y);
            float vz = LEAKY(2.f * hd.z), vw = LEAKY(2.f * hd.w);
            float p0 = vx * a0q.x + vy * a0q.y + vz * a0q.z + vw * a0q.w;
            float p1 = vx * a1q.x + vy * a1q.y + vz * a1q.z + vw * a1q.w;
            p0 = red16(p0);
            p1 = red16(p1);
            float e0 = 0.25f * __expf(p0), e1 = 0.25f * __expf(p1);
            s0 = e0; s1 = e1;
            A0.x = e0 * hd.x; A0.y = e0 * hd.y; A0.z = e0 * hd.z; A0.w = e0 * hd.w;
            A1.x = e1 * hd.x; A1.y = e1 * hd.y; A1.z = e1 * hd.z; A1.w = e1 * hd.w;
        }

        // main loop: subgroup takes edge pairs (2p, 2p+1) — one u32 = 2 indices
        int npair = deg >> 1;
        for (int p = sub; p < npair; p += 4) {
            unsigned pk = rowu[p];
            float4 va = *(const float4*)(hb + (((pk & 0xFFFFu) << 8) + qb));
            float4 vb = *(const float4*)(hb + (((pk >> 16) << 8) + qb));
            float vx, vy, vz, vw;
            vx = LEAKY(va.x + hd.x); vy = LEAKY(va.y + hd.y);
            vz = LEAKY(va.z + hd.z); vw = LEAKY(va.w + hd.w);
            float pa0 = vx * a0q.x + vy * a0q.y + vz * a0q.z + vw * a0q.w;
            float pa1 = vx * a1q.x + vy * a1q.y + vz * a1q.z + vw * a1q.w;
            vx = LEAKY(vb.x + hd.x); vy = LEAKY(vb.y + hd.y);
            vz = LEAKY(vb.z + hd.z); vw = LEAKY(vb.w + hd.w);
            float pb0 = vx * a0q.x + vy * a0q.y + vz * a0q.z + vw * a0q.w;
            float pb1 = vx * a1q.x + vy * a1q.y + vz * a1q.z + vw * a1q.w;
            pa0 = red16(pa0); pa1 = red16(pa1);
            pb0 = red16(pb0); pb1 = red16(pb1);
            float ea0 = __expf(pa0), ea1 = __expf(pa1);
            float eb0 = __expf(pb0), eb1 = __expf(pb1);
            s0 += ea0 + eb0;
            s1 += ea1 + eb1;
            A0.x += ea0 * va.x + eb0 * vb.x; A0.y += ea0 * va.y + eb0 * vb.y;
            A0.z += ea0 * va.z + eb0 * vb.z; A0.w += ea0 * va.w + eb0 * vb.w;
            A1.x += ea1 * va.x + eb1 * vb.x; A1.y += ea1 * va.y + eb1 * vb.y;
            A1.z += ea1 * va.z + eb1 * vb.z; A1.w += ea1 * va.w + eb1 * vb.w;
        }

        // tail: one odd edge, handled by one subgroup (uniform per subgroup)
        if (deg & 1) {
            int t = deg - 1;
            if (sub == ((t >> 1) & 3)) {
                unsigned s = ((const unsigned short*)rowu)[t];
                float4 hv = *(const float4*)(hb + ((s << 8) + qb));
                float vx = LEAKY(hv.x + hd.x), vy = LEAKY(hv.y + hd.y);
                float vz = LEAKY(hv.z + hd.z), vw = LEAKY(hv.w + hd.w);
                float p0 = vx * a0q.x + vy * a0q.y + vz * a0q.z + vw * a0q.w;
                float p1 = vx * a1q.x + vy * a1q.y + vz * a1q.z + vw * a1q.w;
                p0 = red16(p0);
                p1 = red16(p1);
                float e0 = __expf(p0), e1 = __expf(p1);
                s0 += e0; s1 += e1;
                A0.x += e0 * hv.x; A0.y += e0 * hv.y;
                A0.z += e0 * hv.z; A0.w += e0 * hv.w;
                A1.x += e1 * hv.x; A1.y += e1 * hv.y;
                A1.z += e1 * hv.z; A1.w += e1 * hv.w;
            }
        }

        // merge the 4 subgroups: plain sums (cross-row — DPP can't, keep shfl)
#pragma unroll
        for (int step = 16; step <= 32; step <<= 1) {
            s0 += __shfl_xor(s0, step);
            s1 += __shfl_xor(s1, step);
            A0.x += __shfl_xor(A0.x, step); A0.y += __shfl_xor(A0.y, step);
            A0.z += __shfl_xor(A0.z, step); A0.w += __shfl_xor(A0.w, step);
            A1.x += __shfl_xor(A1.x, step); A1.y += __shfl_xor(A1.y, step);
            A1.z += __shfl_xor(A1.z, step); A1.w += __shfl_xor(A1.w, step);
        }

        if (sub == 0) {
            float inv0 = 0.5f / (s0 + 1e-16f);       // fold mean-over-heads
            float inv1 = 0.5f / (s1 + 1e-16f);
            float4 o;
            o.x = A0.x * inv0 + A1.x * inv1 + b4.x;
            o.y = A0.y * inv0 + A1.y * inv1 + b4.y;
            o.z = A0.z * inv0 + A1.z * inv1 + b4.z;
            o.w = A0.w * inv0 + A1.w * inv1 + b4.w;
            ((float4*)h_out)[(size_t)node * 16 + q] = o;
            float4* accp = (float4*)acc + (size_t)node * 16 + q;
            float4 ac;
            if (FIRST) {
                // acc = 0.25*(x + h1); hd holds x's row quad
                ac.x = 0.25f * (hd.x + o.x); ac.y = 0.25f * (hd.y + o.y);
                ac.z = 0.25f * (hd.z + o.z); ac.w = 0.25f * (hd.w + o.w);
            } else {
                ac = *accp;
                ac.x += 0.25f * o.x; ac.y += 0.25f * o.y;
                ac.z += 0.25f * o.z; ac.w += 0.25f * o.w;
            }
            *accp = ac;
        }
    }
}

__global__ __launch_bounds__(256, 6) void k_all(const float* __restrict__ x,
                                                const int* __restrict__ ei,
                                                const float* __restrict__ att,
                                                const float* __restrict__ bias,
                                                int* __restrict__ bcnt,
                                                int* __restrict__ cnt,
                                                unsigned int* __restrict__ bucket,
                                                unsigned short* __restrict__ slots,
                                                float* __restrict__ hA,
                                                float* __restrict__ hB,
                                                float* __restrict__ acc) {
    cooperative_groups::grid_group grid = cooperative_groups::this_grid();

    __shared__ unsigned int stash[CHUNK];    // 8 KB
    __shared__ int hist[NB];                 // 3.1 KB (reused as base after flush)
    __shared__ int rankq[NB];                // 3.1 KB
    __shared__ int lcnt[64];                 // 0.25 KB -> 14.9 KB total

    // ---- phase 0: zero bcnt (replaces the memset dispatch) ----
    for (int i = blockIdx.x * 256 + threadIdx.x; i < NB; i += gridDim.x * 256)
        bcnt[i] = 0;
    grid.sync();

    // ---- phase 1: bin (R13 k_bin, 256 threads / CHUNK=2048) ----
    for (int c = blockIdx.x; c < NCHUNK; c += gridDim.x) {
        int c0 = c * CHUNK;
        int n = EE - c0; if (n > CHUNK) n = CHUNK;
        for (int b = threadIdx.x; b < NB; b += 256) { hist[b] = 0; rankq[b] = 0; }
        __syncthreads();
        for (int k = threadIdx.x; k < n; k += 256) {
            unsigned s = (unsigned)ei[c0 + k];
            unsigned d = (unsigned)ei[EE + c0 + k];
            stash[k] = (d << 16) | s;
            atomicAdd(&hist[d >> 6], 1);
        }
        __syncthreads();
        for (int b = threadIdx.x; b < NB; b += 256) {
            int cc = hist[b];
            hist[b] = cc ? atomicAdd(&bcnt[b], cc) : 0;   // hist now holds base
        }
        __syncthreads();
        for (int k = threadIdx.x; k < n; k += 256) {
            unsigned pk = stash[k];
            int b = (int)(pk >> 22);
            int r = atomicAdd(&rankq[b], 1);
            int pos = hist[b] + r;
            if (pos < BCAP) bucket[(size_t)b * BCAP + pos] = pk;
        }
        __syncthreads();                     // hist/rankq reused next chunk
    }
    grid.sync();

    // ---- phase 2: place (R13 k_place verbatim; block owns 8KB slot window) ----
    for (int b = blockIdx.x; b < NB; b += gridDim.x) {
        if (threadIdx.x < 64) lcnt[threadIdx.x] = 0;
        __syncthreads();
        int node0 = b << 6;
        int m = bcnt[b];
        if (m > BCAP) m = BCAP;
        const unsigned int* src = bucket + (size_t)b * BCAP;
        for (int i = threadIdx.x; i < m; i += 256) {
            unsigned int pk = src[i];
            int d = (int)(pk >> 16);
            int pos = atomicAdd(&lcnt[d - node0], 1);
            if (pos < CAP) slots[(size_t)d * CAP + pos] = (unsigned short)(pk & 0xFFFFu);
        }
        __syncthreads();
        if (threadIdx.x < 64) {
            int node = node0 + threadIdx.x;
            if (node < NN) cnt[node] = lcnt[threadIdx.x];
        }
        __syncthreads();                     // lcnt reused next bucket
    }
    grid.sync();

    // ---- phases 3-5: fused GAT layers (R13 k_gat bodies) ----
    gat_phase<true>(x, cnt, slots, att, bias, hA, acc);
    grid.sync();
    gat_phase<false>(hA, cnt, slots, att + (size_t)HH * CC, bias + CC, hB, acc);
    grid.sync();
    gat_phase<false>(hB, cnt, slots, att + (size_t)2 * HH * CC, bias + 2 * CC, hA, acc);
}

// ---------------- launch ----------------

static inline size_t align256(size_t x) { return (x + 255) & ~(size_t)255; }

extern "C" void kernel_launch(void* const* d_in, const int* in_sizes, int n_in,
                              void* d_out, int out_size, void* d_ws, size_t ws_size,
                              hipStream_t stream) {
    const float* x    = (const float*)d_in[0];
    const int*   ei   = (const int*)d_in[1];
    const float* att  = (const float*)d_in[2];
    const float* bias = (const float*)d_in[3];
    float* acc = (float*)d_out;   // fp32 output; feats-mean accumulated here

    char* w = (char*)d_ws;
    int* bcnt   = (int*)w;              w += align256((size_t)NB * sizeof(int));
    int* cnt    = (int*)w;              w += align256((size_t)NN * sizeof(int));
    unsigned int* bucket = (unsigned int*)w;
    w += align256((size_t)NB * BCAP * sizeof(unsigned int));
    unsigned short* slots = (unsigned short*)w;
    w += align256((size_t)NN * CAP * sizeof(unsigned short));
    float* hA   = (float*)w;            w += align256((size_t)NN * CC * sizeof(float));
    float* hB   = (float*)w;            w += align256((size_t)NN * CC * sizeof(float));

    // grid sized once from the occupancy API so cooperative launch can't fail;
    // all in-kernel loops stride by gridDim.x, so any grid size is correct.
    static int g_grid = 0;
    if (g_grid == 0) {
        int nb = 0;
        if (hipOccupancyMaxActiveBlocksPerMultiprocessor(&nb, k_all, 256, 0)
                != hipSuccess || nb < 1)
            nb = 1;
        long cap = (long)nb * 256;                    // 256 CUs on MI355X
        g_grid = (int)(cap < MAXGRID ? cap : MAXGRID);
    }

    void* args[] = {(void*)&x, (void*)&ei, (void*)&att, (void*)&bias,
                    (void*)&bcnt, (void*)&cnt, (void*)&bucket, (void*)&slots,
                    (void*)&hA, (void*)&hB, (void*)&acc};
    hipLaunchCooperativeKernel(k_all, dim3(g_grid), dim3(256), args, 0, stream);
}

// Round 5
// 196.135 us; speedup vs baseline: 3.4390x; 3.4390x over previous
//
#include <hip/hip_runtime.h>
#include <hip/hip_bf16.h>

#define NN 50000
#define EE 800000
#define CC 64
#define HH 2
#define LL 3
#define CAP 64     // slots per node (Poisson(16): P(>=64) ~ 1e-13)
#define NB 782     // dst buckets of 64 nodes: (50000+63)/64
#define BCAP 1280  // per-bucket capacity (mean 1023, +8 sigma)
#define CHUNK 8192 // edges per k_bin block
#define NBLK ((EE + CHUNK - 1) / CHUNK)   // 98

// R16 = R13 baseline (multi-dispatch; coop fusion R15 regressed 3.4x: grid.sync
// across 8 non-coherent XCD L2s costs ~100us+, not ~2us) + packed-fp32 math in
// k_gat (v_pk_add/mul/fma_f32 via float2 ext_vector, ~24% VALU-issue cut) +
// unroll-2 of the gather loop (batches 2 iterations' independent loads).

// ---------------- build (R13 verbatim) ----------------

__global__ __launch_bounds__(1024) void k_bin(const int* __restrict__ ei,
                                              int* __restrict__ bcnt,
                                              unsigned int* __restrict__ bucket) {
    __shared__ unsigned int stash[CHUNK];
    __shared__ int hist[NB];
    __shared__ int rank[NB];
    __shared__ int base[NB];

    int c0 = blockIdx.x * CHUNK;
    int n = EE - c0; if (n > CHUNK) n = CHUNK;

    for (int b = threadIdx.x; b < NB; b += 1024) { hist[b] = 0; rank[b] = 0; }
    __syncthreads();

    for (int k = threadIdx.x; k < n; k += 1024) {
        unsigned int s = (unsigned int)ei[c0 + k];
        unsigned int d = (unsigned int)ei[EE + c0 + k];
        stash[k] = (d << 16) | s;
        atomicAdd(&hist[d >> 6], 1);
    }
    __syncthreads();

    for (int b = threadIdx.x; b < NB; b += 1024) {
        int c = hist[b];
        base[b] = c ? atomicAdd(&bcnt[b], c) : 0;
    }
    __syncthreads();

    for (int k = threadIdx.x; k < n; k += 1024) {
        unsigned int pk = stash[k];
        int b = (int)(pk >> 22);
        int r = atomicAdd(&rank[b], 1);
        int pos = base[b] + r;
        if (pos < BCAP) bucket[(size_t)b * BCAP + pos] = pk;
    }
}

__global__ __launch_bounds__(256) void k_place(const unsigned int* __restrict__ bucket,
                                               const int* __restrict__ bcnt,
                                               int* __restrict__ cnt,
                                               unsigned short* __restrict__ slots) {
    __shared__ int lcnt[64];
    int b = blockIdx.x;
    if (threadIdx.x < 64) lcnt[threadIdx.x] = 0;
    __syncthreads();
    int node0 = b << 6;
    int m = bcnt[b];
    if (m > BCAP) m = BCAP;
    const unsigned int* src = bucket + (size_t)b * BCAP;
    for (int i = threadIdx.x; i < m; i += 256) {
        unsigned int pk = src[i];
        int d = (int)(pk >> 16);
        int s = (int)(pk & 0xFFFFu);
        int pos = atomicAdd(&lcnt[d - node0], 1);
        if (pos < CAP) slots[(size_t)d * CAP + pos] = (unsigned short)s;
    }
    __syncthreads();
    if (threadIdx.x < 64) {
        int node = node0 + threadIdx.x;
        if (node < NN) cnt[node] = lcnt[threadIdx.x];
    }
}

// ---------------- fused GAT layer ----------------
// R13 structure: wave per node; 4 subgroups x 16 lanes; lane holds one channel
// quad (ONE contiguous dwordx4 per row per lane — proven coalescing). Per-edge
// reduce via fused v_add_f32_dpp (VALU pipe, no lgkm stall). NEW in R16:
// elementwise math in float2 ext_vectors -> v_pk_{add,mul,fma}_f32.

typedef float v2f __attribute__((ext_vector_type(2)));

template <int CTRL>
__device__ __forceinline__ float dpp_add(float v) {
    int t = __builtin_amdgcn_update_dpp(0, __float_as_int(v), CTRL, 0xF, 0xF, true);
    return v + __int_as_float(t);
}

// sum over the 16 lanes of a subgroup (subgroups are 16-lane aligned)
__device__ __forceinline__ float red16(float v) {
    v = dpp_add<0xB1>(v);    // quad_perm [1,0,3,2] = lane^1
    v = dpp_add<0x4E>(v);    // quad_perm [2,3,0,1] = lane^2
    v = dpp_add<0x141>(v);   // row_half_mirror     = lane^4 (quads uniform)
    v = dpp_add<0x140>(v);   // row_mirror          = lane^8 (halves uniform)
    return v;
}

// leaky_relu on a packed pair: pk_mul + 2x v_max
__device__ __forceinline__ v2f lk2(v2f v) {
    v2f t = 0.2f * v;
    return __builtin_elementwise_max(v, t);
}

__device__ __forceinline__ v2f fma2(v2f a, v2f b, v2f c) {
    return __builtin_elementwise_fma(a, b, c);
}

template <bool FIRST>
__global__ __launch_bounds__(256) void k_gat(const float* __restrict__ h,
                                             const int* __restrict__ cnt,
                                             const unsigned short* __restrict__ slots,
                                             const float* __restrict__ att_l,
                                             const float* __restrict__ bias_l,
                                             float* __restrict__ h_out,
                                             float* __restrict__ acc, int n) {
    int wid = threadIdx.x >> 6;
    int lane = threadIdx.x & 63;
    int node = blockIdx.x * 4 + wid;
    if (node >= n) return;
    int sub = lane >> 4, q = lane & 15;
    unsigned qb = (unsigned)q << 4;              // byte offset of quad in a row
    const char* hb = (const char*)h;
    const v2f* attv = (const v2f*)att_l;
    v2f a0_01 = attv[2 * q],      a0_23 = attv[2 * q + 1];
    v2f a1_01 = attv[32 + 2 * q], a1_23 = attv[32 + 2 * q + 1];
    float4 hd = *(const float4*)(hb + (((unsigned)node << 8) + qb));
    v2f hd01 = {hd.x, hd.y}, hd23 = {hd.z, hd.w};
    int deg = cnt[node];
    if (deg > CAP) deg = CAP;
    const unsigned* rowu = (const unsigned*)(slots + (size_t)node * CAP);

    float s0, s1;
    v2f A0_01, A0_23, A1_01, A1_23;

    // self-loop: all 4 subgroups, weight 1/4 (merge sums restore 1x) — no branch
    {
        v2f u01 = lk2(hd01 + hd01), u23 = lk2(hd23 + hd23);
        v2f d0 = fma2(u23, a0_23, u01 * a0_01);
        v2f d1 = fma2(u23, a1_23, u01 * a1_01);
        float p0 = red16(d0.x + d0.y);
        float p1 = red16(d1.x + d1.y);
        float e0 = 0.25f * __expf(p0), e1 = 0.25f * __expf(p1);
        s0 = e0; s1 = e1;
        A0_01 = e0 * hd01; A0_23 = e0 * hd23;
        A1_01 = e1 * hd01; A1_23 = e1 * hd23;
    }

    // main loop: subgroup takes edge pairs (2p, 2p+1) — one u32 = both indices.
    // unroll 2: batches two iterations' independent rowu/va/vb loads.
    int npair = deg >> 1;
#pragma unroll 2
    for (int p = sub; p < npair; p += 4) {
        unsigned pk = rowu[p];
        float4 va = *(const float4*)(hb + (((pk & 0xFFFFu) << 8) + qb));
        float4 vb = *(const float4*)(hb + (((pk >> 16) << 8) + qb));
        v2f va01 = {va.x, va.y}, va23 = {va.z, va.w};
        v2f vb01 = {vb.x, vb.y}, vb23 = {vb.z, vb.w};
        v2f ma01 = lk2(va01 + hd01), ma23 = lk2(va23 + hd23);
        v2f mb01 = lk2(vb01 + hd01), mb23 = lk2(vb23 + hd23);
        v2f da0 = fma2(ma23, a0_23, ma01 * a0_01);
        v2f da1 = fma2(ma23, a1_23, ma01 * a1_01);
        v2f db0 = fma2(mb23, a0_23, mb01 * a0_01);
        v2f db1 = fma2(mb23, a1_23, mb01 * a1_01);
        float pa0 = red16(da0.x + da0.y);
        float pa1 = red16(da1.x + da1.y);
        float pb0 = red16(db0.x + db0.y);
        float pb1 = red16(db1.x + db1.y);
        float ea0 = __expf(pa0), ea1 = __expf(pa1);
        float eb0 = __expf(pb0), eb1 = __expf(pb1);
        s0 += ea0 + eb0;
        s1 += ea1 + eb1;
        v2f ea0v = {ea0, ea0}, ea1v = {ea1, ea1};
        v2f eb0v = {eb0, eb0}, eb1v = {eb1, eb1};
        A0_01 = fma2(ea0v, va01, fma2(eb0v, vb01, A0_01));
        A0_23 = fma2(ea0v, va23, fma2(eb0v, vb23, A0_23));
        A1_01 = fma2(ea1v, va01, fma2(eb1v, vb01, A1_01));
        A1_23 = fma2(ea1v, va23, fma2(eb1v, vb23, A1_23));
    }

    // tail: one odd edge, handled by one subgroup (uniform per subgroup)
    if (deg & 1) {
        int t = deg - 1;
        if (sub == ((t >> 1) & 3)) {
            unsigned s = ((const unsigned short*)rowu)[t];
            float4 hv = *(const float4*)(hb + ((s << 8) + qb));
            v2f hv01 = {hv.x, hv.y}, hv23 = {hv.z, hv.w};
            v2f m01 = lk2(hv01 + hd01), m23 = lk2(hv23 + hd23);
            v2f d0 = fma2(m23, a0_23, m01 * a0_01);
            v2f d1 = fma2(m23, a1_23, m01 * a1_01);
            float p0 = red16(d0.x + d0.y);
            float p1 = red16(d1.x + d1.y);
            float e0 = __expf(p0), e1 = __expf(p1);
            s0 += e0; s1 += e1;
            v2f e0v = {e0, e0}, e1v = {e1, e1};
            A0_01 = fma2(e0v, hv01, A0_01); A0_23 = fma2(e0v, hv23, A0_23);
            A1_01 = fma2(e1v, hv01, A1_01); A1_23 = fma2(e1v, hv23, A1_23);
        }
    }

    // merge the 4 subgroups: plain sums (cross-row — DPP can't, keep shfl)
#pragma unroll
    for (int step = 16; step <= 32; step <<= 1) {
        s0 += __shfl_xor(s0, step);
        s1 += __shfl_xor(s1, step);
        A0_01.x += __shfl_xor(A0_01.x, step); A0_01.y += __shfl_xor(A0_01.y, step);
        A0_23.x += __shfl_xor(A0_23.x, step); A0_23.y += __shfl_xor(A0_23.y, step);
        A1_01.x += __shfl_xor(A1_01.x, step); A1_01.y += __shfl_xor(A1_01.y, step);
        A1_23.x += __shfl_xor(A1_23.x, step); A1_23.y += __shfl_xor(A1_23.y, step);
    }

    if (sub == 0) {
        float inv0 = 0.5f / (s0 + 1e-16f);       // fold mean-over-heads
        float inv1 = 0.5f / (s1 + 1e-16f);
        float4 b4 = ((const float4*)bias_l)[q];
        float4 o;
        o.x = A0_01.x * inv0 + A1_01.x * inv1 + b4.x;
        o.y = A0_01.y * inv0 + A1_01.y * inv1 + b4.y;
        o.z = A0_23.x * inv0 + A1_23.x * inv1 + b4.z;
        o.w = A0_23.y * inv0 + A1_23.y * inv1 + b4.w;
        ((float4*)h_out)[(size_t)node * 16 + q] = o;
        float4* accp = (float4*)acc + (size_t)node * 16 + q;
        float4 ac;
        if (FIRST) {
            // acc = 0.25*(x + h1); hd holds x's row quad
            ac.x = 0.25f * (hd.x + o.x); ac.y = 0.25f * (hd.y + o.y);
            ac.z = 0.25f * (hd.z + o.z); ac.w = 0.25f * (hd.w + o.w);
        } else {
            ac = *accp;
            ac.x += 0.25f * o.x; ac.y += 0.25f * o.y;
            ac.z += 0.25f * o.z; ac.w += 0.25f * o.w;
        }
        *accp = ac;
    }
}

// ---------------- launch ----------------

static inline size_t align256(size_t x) { return (x + 255) & ~(size_t)255; }

extern "C" void kernel_launch(void* const* d_in, const int* in_sizes, int n_in,
                              void* d_out, int out_size, void* d_ws, size_t ws_size,
                              hipStream_t stream) {
    const float* x    = (const float*)d_in[0];
    const int*   ei   = (const int*)d_in[1];
    const float* att  = (const float*)d_in[2];
    const float* bias = (const float*)d_in[3];
    float* acc = (float*)d_out;   // fp32 output; feats-mean accumulated here

    char* w = (char*)d_ws;
    int* bcnt   = (int*)w;              w += align256((size_t)NB * sizeof(int));
    int* cnt    = (int*)w;              w += align256((size_t)NN * sizeof(int));
    unsigned int* bucket = (unsigned int*)w;
    w += align256((size_t)NB * BCAP * sizeof(unsigned int));
    unsigned short* slots = (unsigned short*)w;
    w += align256((size_t)NN * CAP * sizeof(unsigned short));
    float* hA   = (float*)w;            w += align256((size_t)NN * CC * sizeof(float));
    float* hB   = (float*)w;            w += align256((size_t)NN * CC * sizeof(float));

    const int B = 256;

    // build (per call; ws is re-poisoned before every launch)
    hipMemsetAsync(bcnt, 0, (size_t)NB * sizeof(int), stream);
    k_bin<<<NBLK, 1024, 0, stream>>>(ei, bcnt, bucket);
    k_place<<<NB, B, 0, stream>>>(bucket, bcnt, cnt, slots);

    // 3 fused GAT layers; layer 0 reads x directly and seeds acc = 0.25*(x + h1)
    k_gat<true><<<(NN + 3) / 4, B, 0, stream>>>(
        x, cnt, slots, att, bias, hA, acc, NN);
    k_gat<false><<<(NN + 3) / 4, B, 0, stream>>>(
        hA, cnt, slots, att + (size_t)HH * CC, bias + CC, hB, acc, NN);
    k_gat<false><<<(NN + 3) / 4, B, 0, stream>>>(
        hB, cnt, slots, att + (size_t)2 * HH * CC, bias + 2 * CC, hA, acc, NN);
}